// Round 9
// baseline (159.347 us; speedup 1.0000x reference)
//
#include <hip/hip_runtime.h>
#include <hip/hip_bf16.h>
#include <math.h>

#define EDIM 256
#define HDIM 256
#define BDIM 64
#define TDIM 2048
#define NC   64
#define TC   32

typedef __attribute__((ext_vector_type(8)))  short  short8;
typedef __attribute__((ext_vector_type(4)))  float  floatx4;
typedef __attribute__((ext_vector_type(4)))  unsigned int uintx4;

__device__ __forceinline__ unsigned short f2bf(float f) {
    unsigned int u = __float_as_uint(f);
    u += 0x7FFFu + ((u >> 16) & 1u);      // RNE
    return (unsigned short)(u >> 16);
}
__device__ __forceinline__ unsigned int pk2(float a, float b) {
    return (unsigned int)f2bf(a) | ((unsigned int)f2bf(b) << 16);
}
__device__ __forceinline__ float sigm(float x) {
    return __builtin_amdgcn_rcpf(1.f + __expf(-x));
}
__device__ __forceinline__ float tanh_fast(float x) {
    return fmaf(-2.f, __builtin_amdgcn_rcpf(1.f + __expf(2.f * x)), 1.f);
}

// Pack kernel:
//  bx < 256 : Wp fragment-pack (R0 layout).
//  bx >= 256 (mode==1): emb -> bf16 table.
__global__ __launch_bounds__(256) void qrnn_pack(
    const float* __restrict__ Wq, const float* __restrict__ emb,
    unsigned short* __restrict__ Wp, unsigned short* __restrict__ ebf,
    int mode)
{
    const int bx = blockIdx.x;
    if (bx < 256) {
        const int nt = (bx >> 3) & 7;
        const int hg = bx >> 6;
        const int ks = bx & 7;
        const int t = threadIdx.x;
        const int lane = t >> 2, pj = t & 3;
        const int col = lane & 15, q = lane >> 4;
        const int h = hg * 64 + (nt & 3) * 16 + col;
        const int c = (nt < 4) ? h : (HDIM + h);
        const int k = ks * 32 + q * 8 + pj * 2;
        unsigned int v = pk2(Wq[k * (3 * HDIM) + c], Wq[(k + 1) * (3 * HDIM) + c]);
        *(unsigned int*)(Wp + (size_t)bx * 512 + lane * 8 + pj * 2) = v;
    } else if (mode == 1) {
        size_t i = ((size_t)(bx - 256) * 256 + threadIdx.x) * 8;
        floatx4 a = *(const floatx4*)(emb + i);
        floatx4 b = *(const floatx4*)(emb + i + 4);
        uintx4 o = {pk2(a.x, a.y), pk2(a.z, a.w), pk2(b.x, b.y), pk2(b.z, b.w)};
        *(uintx4*)(ebf + i) = o;
    }
}

// Main: hg FOLDED INTO THE BLOCK to kill the 4x redundant A-gather.
// Grid (64 chunks, 8 bg) = 512 blocks x 512 thr (8 waves, 1 batch/wave),
// 64KB LDS -> 2 blocks/CU.  Per block: gather the chunk's A-fragments ONCE
// (abuf[8][2], 64 VGPR, pinned by sched_barrier + staging-barrier vmcnt
// drain), then loop hg=0..3: restage Bsh (64KB, L2-hot Wp, coalesced
// global_load_lds; hg+1 staged under the epilogue), 8 ks-steps of MFMA
// reusing abuf, epilogue, store.  Scattered line-requests/CU drop 4x
// (16K -> 4K); MFMA/LDS/output work unchanged.
template<int MODE>
__global__ __launch_bounds__(512, 2) void qrnn_mfma(
    const int* __restrict__ X, const float* __restrict__ emb,
    const unsigned short* __restrict__ ebf, const unsigned short* __restrict__ Wp,
    const float* __restrict__ bq, float* __restrict__ wsA, float* __restrict__ wsB)
{
    __shared__ __align__(16) short Bsh[32768];   // 64 KB: [nt*8+ks][64 lanes][8]

    const int tid = threadIdx.x;
    const int cg = blockIdx.x, bg = blockIdx.y;  // cg = chunk index (0..63)
    const int lane = tid & 63, w = tid >> 6;     // w in [0,8)
    const int col = lane & 15, q = lane >> 4;

    const int b0 = bg * 8 + w;                   // one batch per wave
    int xid[2];
#pragma unroll
    for (int mt = 0; mt < 2; ++mt)
        xid[mt] = X[b0 * TDIM + cg * TC + mt * 16 + col];

    // ---- A-burst: entire chunk's fragments, gathered ONCE. ----
    short8 abuf[8][2];
#pragma unroll
    for (int ks = 0; ks < 8; ++ks)
#pragma unroll
        for (int mt = 0; mt < 2; ++mt) {
            if constexpr (MODE == 1) {
                abuf[ks][mt] = *(const short8*)(ebf + (size_t)xid[mt] * EDIM + q * 8 + ks * 32);
            } else {
                const float* ap = emb + (size_t)xid[mt] * EDIM + q * 8 + ks * 32;
                floatx4 f0 = *(const floatx4*)ap;
                floatx4 f1 = *(const floatx4*)(ap + 4);
                uintx4 p = {pk2(f0.x, f0.y), pk2(f0.z, f0.w),
                            pk2(f1.x, f1.y), pk2(f1.z, f1.w)};
                abuf[ks][mt] = *(short8*)&p;
            }
        }
    __builtin_amdgcn_sched_barrier(0);   // pin: burst issues before staging/barrier

    // Stage Bsh for hg=0 (64 rows / 8 waves = 8 each, wave-uniform dest).
    auto stage = [&](int hg) {
        const unsigned short* wpb = Wp + (size_t)hg * 32768;
#pragma unroll
        for (int i = 0; i < 8; ++i) {
            const int ch = w * 8 + i;
            __builtin_amdgcn_global_load_lds(
                (const __attribute__((address_space(1))) unsigned int*)(wpb + ch * 512 + lane * 8),
                (__attribute__((address_space(3))) unsigned int*)(Bsh + ch * 512),
                16, 0, 0);
        }
    };
    stage(0);
    __syncthreads();   // drains A-burst + hg=0 staging (vmcnt 0)

#pragma unroll 1
    for (int hg = 0; hg < 4; ++hg) {
        const int hbase = hg * 64;
        float bz[4], bff[4];
#pragma unroll
        for (int nt = 0; nt < 4; ++nt) {
            bz[nt]  = bq[hbase + nt * 16 + col];
            bff[nt] = bq[HDIM + hbase + nt * 16 + col];
        }

        floatx4 acc[2][8];
#pragma unroll
        for (int mt = 0; mt < 2; ++mt)
#pragma unroll
            for (int nt = 0; nt < 8; ++nt) acc[mt][nt] = (floatx4){0.f, 0.f, 0.f, 0.f};

#pragma unroll
        for (int ks = 0; ks < 8; ++ks) {
            short8 bf[8];
#pragma unroll
            for (int nt = 0; nt < 8; ++nt)
                bf[nt] = *(const short8*)(Bsh + (nt * 8 + ks) * 512 + lane * 8);
#pragma unroll
            for (int nt = 0; nt < 8; ++nt)
#pragma unroll
                for (int mt = 0; mt < 2; ++mt)
                    acc[mt][nt] = __builtin_amdgcn_mfma_f32_16x16x32_bf16(abuf[ks][mt], bf[nt], acc[mt][nt], 0, 0, 0);
        }

        __syncthreads();                 // all waves done reading Bsh(hg)
        if (hg < 3) stage(hg + 1);       // async restage, hides under epilogue

        // Epilogue: t = q*4 + j (+16*mt), h-col = nt*16+col.
        float Af[4], Bf[4];
#pragma unroll
        for (int nt = 0; nt < 4; ++nt) {
            float Aseg[2], Bseg[2];
#pragma unroll
            for (int mt = 0; mt < 2; ++mt) {
                float Ac = 1.f, Bc = 0.f;
#pragma unroll
                for (int j = 0; j < 4; ++j) {
                    float z = tanh_fast(acc[mt][nt][j] + bz[nt]);
                    float f = sigm(acc[mt][nt + 4][j] + bff[nt]);
                    Ac = f * Ac;
                    Bc = fmaf(f, Bc, (1.f - f) * z);
                }
                Aseg[mt] = Ac; Bseg[mt] = Bc;
            }
#pragma unroll
            for (int st = 0; st < 2; ++st) {
                const int msk = 16 << st;
                const bool self_earlier = ((q >> st) & 1) == 0;
#pragma unroll
                for (int mt = 0; mt < 2; ++mt) {
                    float Ap = __shfl_xor(Aseg[mt], msk, 64);
                    float Bp = __shfl_xor(Bseg[mt], msk, 64);
                    Bseg[mt] = self_earlier ? fmaf(Ap, Bseg[mt], Bp)
                                            : fmaf(Aseg[mt], Bp, Bseg[mt]);
                    Aseg[mt] = Aseg[mt] * Ap;
                }
            }
            Af[nt] = Aseg[0] * Aseg[1];                 // full 32-t chunk, batch b0
            Bf[nt] = fmaf(Aseg[1], Bseg[0], Bseg[1]);
        }

        float As = (q == 0) ? Af[0] : (q == 1) ? Af[1] : (q == 2) ? Af[2] : Af[3];
        float Bs = (q == 0) ? Bf[0] : (q == 1) ? Bf[1] : (q == 2) ? Bf[2] : Bf[3];

        const size_t r0 = ((size_t)cg * BDIM + b0) * HDIM + hbase + lane;
        wsA[r0] = As;
        wsB[r0] = Bs;

        __syncthreads();                 // staging for hg+1 drained (vmcnt 0)
    }
}

// Combine chunk (A,B) pairs + o-gate at t=T-1 + output dot.
__global__ __launch_bounds__(256) void qrnn_combine(
    const float* __restrict__ wsA, const float* __restrict__ wsB,
    const float* __restrict__ c0, const int* __restrict__ X,
    const float* __restrict__ emb, const float* __restrict__ Wq,
    const float* __restrict__ bq, const float* __restrict__ Wout,
    const float* __restrict__ bout, float* __restrict__ out)
{
    const int b = blockIdx.x;
    const int h = threadIdx.x;

    float c = c0[b * HDIM + h];
    for (int c8 = 0; c8 < NC; c8 += 8) {
        float a[8], bb[8];
#pragma unroll
        for (int i = 0; i < 8; ++i) {
            size_t base = ((size_t)(c8 + i) * BDIM + b) * HDIM + h;
            a[i]  = wsA[base];
            bb[i] = wsB[base];
        }
#pragma unroll
        for (int i = 0; i < 8; ++i) c = fmaf(a[i], c, bb[i]);
    }

    __shared__ float xs[EDIM];
    int idx = X[b * TDIM + (TDIM - 1)];
    xs[h] = emb[(size_t)idx * EDIM + h];
    __syncthreads();

    float acc = 0.f;
#pragma unroll 16
    for (int e = 0; e < EDIM; ++e)
        acc = fmaf(xs[e], Wq[e * (3 * HDIM) + 2 * HDIM + h], acc);

    float o  = 1.f / (1.f + expf(-(acc + bq[2 * HDIM + h])));
    float hn = o * c;

    __shared__ float red[HDIM];
    red[h] = hn * Wout[h];
    __syncthreads();
    for (int s = HDIM / 2; s > 0; s >>= 1) {
        if (h < s) red[h] += red[h + s];
        __syncthreads();
    }
    if (h == 0) out[b] = red[0] + bout[0];
}

extern "C" void kernel_launch(void* const* d_in, const int* in_sizes, int n_in,
                              void* d_out, int out_size, void* d_ws, size_t ws_size,
                              hipStream_t stream) {
    const int*   X    = (const int*)d_in[0];
    const float* emb  = (const float*)d_in[1];
    const float* Wq   = (const float*)d_in[2];
    const float* bq   = (const float*)d_in[3];
    const float* c0   = (const float*)d_in[4];
    const float* Wout = (const float*)d_in[5];
    const float* bout = (const float*)d_in[6];
    float* out = (float*)d_out;

    float* wsA = (float*)d_ws;                        // [NC][B][H]
    float* wsB = wsA + (size_t)NC * BDIM * HDIM;      // [NC][B][H]
    unsigned short* Wp  = (unsigned short*)(wsB + (size_t)NC * BDIM * HDIM);  // 256 KB
    unsigned short* ebf = Wp + (size_t)256 * 512;     // 16.4 MB bf16 emb table

    const size_t wsAB = (size_t)2 * NC * BDIM * HDIM * 4;
    const size_t wpsz = (size_t)256 * 512 * 2;
    const size_t need1 = wsAB + wpsz + (size_t)32000 * EDIM * 2;   // ~25.0 MB
    const int mode = (ws_size >= need1) ? 1 : 0;

    const int gather_blocks = (mode == 1) ? (32000 * EDIM / 8) / 256 : 0;  // 4000
    qrnn_pack<<<256 + gather_blocks, 256, 0, stream>>>(Wq, emb, Wp, ebf, mode);

    dim3 g(NC, BDIM / 8, 1);   // 64 x 8 = 512 blocks of 512 thr (2/CU)
    if (mode == 1) qrnn_mfma<1><<<g, 512, 0, stream>>>(X, emb, ebf, Wp, bq, wsA, wsB);
    else           qrnn_mfma<0><<<g, 512, 0, stream>>>(X, emb, ebf, Wp, bq, wsA, wsB);

    qrnn_combine<<<BDIM, 256, 0, stream>>>(wsA, wsB, c0, X, emb, Wq, bq, Wout, bout, out);
}